// Round 2
// baseline (709.389 us; speedup 1.0000x reference)
//
#include <hip/hip_runtime.h>
#include <hip/hip_bf16.h>
#include <cstdint>
#include <cstddef>

#define D_DIM 2048
#define L_SEQ 2048
#define B_SZ 4
#define M_ROWS (B_SZ * L_SEQ)   /* 8192 */
#define NT_COLS (3 * D_DIM)     /* 6144: seg0=A, seg1=dt, seg2=rawB */
#define NCH 16
#define CHUNK (L_SEQ / NCH)     /* 128 */
#define KTILES (D_DIM / 64)     /* 32 */

typedef __bf16 bf16_t;
typedef bf16_t bf16x4 __attribute__((ext_vector_type(4)));
typedef bf16_t bf16x8 __attribute__((ext_vector_type(8)));
typedef float f32x4 __attribute__((ext_vector_type(4)));

__device__ __forceinline__ void gl_lds16(const void* g, void* l) {
    __builtin_amdgcn_global_load_lds(
        (const __attribute__((address_space(1))) unsigned int*)g,
        (__attribute__((address_space(3))) unsigned int*)l, 16, 0, 0);
}

#define BAR() asm volatile("s_barrier" ::: "memory")
#define VMCNT4() asm volatile("s_waitcnt vmcnt(4)" ::: "memory")
#define VMCNT0() asm volatile("s_waitcnt vmcnt(0)" ::: "memory")

// ---------------- convert force f32 -> bf16 (vectorized) ----------------
__global__ __launch_bounds__(256) void cvt_bf16_kernel(
    const float* __restrict__ in, bf16_t* __restrict__ out, int n4)
{
    int i = blockIdx.x * 256 + threadIdx.x;
    if (i >= n4) return;
    float4 f = ((const float4*)in)[i];
    bf16x4 o;
    o[0] = (bf16_t)f.x; o[1] = (bf16_t)f.y; o[2] = (bf16_t)f.z; o[3] = (bf16_t)f.w;
    ((bf16x4*)out)[i] = o;
}

// ---------------- transpose W[k][j] -> Wt[j][k] with f32->bf16 ----------------
__global__ __launch_bounds__(256) void transpose_w_kernel(
    const float* __restrict__ W, bf16_t* __restrict__ Wt)
{
    __shared__ float tile[32][33];
    int j0 = blockIdx.x * 32, k0 = blockIdx.y * 32;
    int tx = threadIdx.x, ty = threadIdx.y;      // block (32, 8)
#pragma unroll
    for (int i = 0; i < 4; i++) {
        int k = k0 + ty + i * 8;
        tile[ty + i * 8][tx] = W[(size_t)k * D_DIM + j0 + tx];
    }
    __syncthreads();
#pragma unroll
    for (int i = 0; i < 4; i++) {
        int j = j0 + ty + i * 8;
        Wt[(size_t)j * D_DIM + k0 + tx] = (bf16_t)tile[tx][ty + i * 8];
    }
}

// ---------------- staging: one 16KB half-tile (256 rows x 32 bf16 cols) ----------
// LDS dest linear (global_load_lds constraint); read-side XOR swizzle
// byte ^= ((row>>1)&3)<<4 is pre-applied to the per-lane GLOBAL column.
__device__ __forceinline__ void stage_half(const bf16_t* gp, int kofs,
                                           char* ldsreg, int w, int lane)
{
    const int r0 = w * 32 + (lane >> 2);
    const int gc = (((lane & 3) ^ ((lane >> 3) & 3)) << 3);   // elements
    gl_lds16(gp + (size_t)r0 * D_DIM + kofs + gc, ldsreg + w * 2048);
    gl_lds16(gp + (size_t)(r0 + 16) * D_DIM + kofs + gc, ldsreg + w * 2048 + 1024);
}

// read 12 frags for one (buf, ks): A mh0 (4), B (4), A mh1 (4) — counted lgkm
#define READ_FRAGS(BUF, KS, AF, BF) {                                          \
    const char* ra_ = lds + (BUF) * 32768 + (KS) * 16384;                      \
    const char* rb_ = ra_ + 65536;                                             \
    _Pragma("unroll") for (int mm = 0; mm < 4; mm++)                           \
        AF[mm] = *(const bf16x8*)(ra_ + ((wmBase + mm * 16) << 6) + loff);     \
    _Pragma("unroll") for (int nn = 0; nn < 4; nn++)                           \
        BF[nn] = *(const bf16x8*)(rb_ + ((wnBase + nn * 16) << 6) + loff);     \
    _Pragma("unroll") for (int mm = 4; mm < 8; mm++)                           \
        AF[mm] = *(const bf16x8*)(ra_ + ((wmBase + mm * 16) << 6) + loff); }

#define MFMA_QUAD(MH, AF, BF)                                                  \
    __builtin_amdgcn_s_setprio(1);                                             \
    _Pragma("unroll") for (int mm = 0; mm < 4; mm++)                           \
        _Pragma("unroll") for (int nn = 0; nn < 4; nn++)                       \
            acc[(MH) * 4 + mm][nn] = __builtin_amdgcn_mfma_f32_16x16x32_bf16(  \
                AF[(MH) * 4 + mm], BF[nn], acc[(MH) * 4 + mm][nn], 0, 0, 0);   \
    __builtin_amdgcn_s_setprio(0);

#define STAGE_A(BUF, T, KS) stage_half(gA, (T) * 64 + (KS) * 32,               \
        lds + (BUF) * 32768 + (KS) * 16384, w, lane)
#define STAGE_B(BUF, T, KS) stage_half(gB, (T) * 64 + (KS) * 32,               \
        lds + 65536 + (BUF) * 32768 + (KS) * 16384, w, lane)

// ---------------- fused bf16 GEMM: [8192 x 2048] @ [2048 x 6144] ----------------
// 256x256 tile, BK=64, 8 waves (2x4), 8-phase counted-vmcnt schedule (T1-T5).
__global__ __launch_bounds__(512, 2) void gemm_fused_kernel(
    const bf16_t* __restrict__ Abf,   // force bf16 [8192][2048]
    const bf16_t* __restrict__ Wt,    // [6144][2048] (W^T, concat A|dt|B)
    const float* __restrict__ bA, const float* __restrict__ bdt,
    const float* __restrict__ bB, const float* __restrict__ scales,
    float* __restrict__ outA,         // -> d_out x-region (staging)
    float* __restrict__ outDT,        // -> ws
    float* __restrict__ outB)         // -> d_out v-region (staging)
{
    __shared__ __align__(1024) char lds[131072];   // A: [2buf][2ks][256][64B]; B at +65536

    // XCD-aware bijective swizzle: 768 blocks, 96 per XCD = 4 m-tiles x 24 n-tiles
    const int bid = blockIdx.x;
    const int u = (bid & 7) * 96 + (bid >> 3);
    const int bm0 = (u / 24) * 256;
    const int bn0 = (u % 24) * 256;

    const int tid = threadIdx.x;
    const int lane = tid & 63;
    const int w = tid >> 6;          // 0..7
    const int wm = w >> 2;           // 0..1
    const int wn = w & 3;            // 0..3
    const int wmBase = wm * 128;
    const int wnBase = wn * 64;

    // per-lane LDS read offset (frag): row=frow within 16-row group, slot XOR-swizzled
    const int frow = lane & 15;
    const int loff = frow * 64 + (((lane >> 4) << 4) ^ (((frow >> 1) & 3) << 4));

    const bf16_t* gA = Abf + (size_t)bm0 * D_DIM;
    const bf16_t* gB = Wt + (size_t)bn0 * D_DIM;

    f32x4 acc[8][4] = {};
    bf16x8 af0[8], af1[8], bf0[4], bf1[4];

    // -------- prologue: tile0 (all 4 halves) + tile1 (ks0 halves) --------
    STAGE_A(0, 0, 0); STAGE_B(0, 0, 0); STAGE_A(0, 0, 1); STAGE_B(0, 0, 1);
    STAGE_A(1, 1, 0); STAGE_B(1, 1, 0);
    VMCNT4();                         // tile0 landed; tile1.ks0 in flight
    BAR();

    // -------- main loop: 16 iterations x 2 K-tiles --------
    for (int i = 0; i < KTILES / 2; ++i) {
        const int t = 2 * i;
        const bool nl = (i < KTILES / 2 - 1);

        // ph1: reads buf0.ks0 | stage A(t+1,ks1)->buf1 | mfma t (mh0, ks0)
        READ_FRAGS(0, 0, af0, bf0);
        STAGE_A(1, t + 1, 1);
        BAR();
        MFMA_QUAD(0, af0, bf0);
        BAR();
        // ph2: reads buf0.ks1 | stage B(t+1,ks1)->buf1 | mfma t (mh1, ks0)
        READ_FRAGS(0, 1, af1, bf1);
        STAGE_B(1, t + 1, 1);
        BAR();
        MFMA_QUAD(1, af0, bf0);
        BAR();
        // ph3: stage A(t+2,ks0)->buf0 | mfma t (mh0, ks1)
        if (nl) STAGE_A(0, t + 2, 0);
        BAR();
        MFMA_QUAD(0, af1, bf1);
        BAR();
        // ph4: stage B(t+2,ks0)->buf0 | mfma t (mh1, ks1) | vmcnt gate for t+1
        if (nl) STAGE_B(0, t + 2, 0);
        BAR();
        MFMA_QUAD(1, af1, bf1);
        if (nl) { VMCNT4(); } else { VMCNT0(); }
        BAR();
        // ph5: reads buf1.ks0 | stage A(t+2,ks1)->buf0 | mfma t+1 (mh0, ks0)
        READ_FRAGS(1, 0, af0, bf0);
        if (nl) STAGE_A(0, t + 2, 1);
        BAR();
        MFMA_QUAD(0, af0, bf0);
        BAR();
        // ph6: reads buf1.ks1 | stage B(t+2,ks1)->buf0 | mfma t+1 (mh1, ks0)
        READ_FRAGS(1, 1, af1, bf1);
        if (nl) STAGE_B(0, t + 2, 1);
        BAR();
        MFMA_QUAD(1, af0, bf0);
        BAR();
        // ph7: stage A(t+3,ks0)->buf1 | mfma t+1 (mh0, ks1)
        if (nl) STAGE_A(1, t + 3, 0);
        BAR();
        MFMA_QUAD(0, af1, bf1);
        BAR();
        // ph8: stage B(t+3,ks0)->buf1 | mfma t+1 (mh1, ks1) | vmcnt gate for t+2
        if (nl) STAGE_B(1, t + 3, 0);
        BAR();
        MFMA_QUAD(1, af1, bf1);
        if (nl) { VMCNT4(); }
        BAR();
    }

    // -------- epilogue: C/D layout col = lane&15, row = (lane>>4)*4 + reg --------
    const int seg = bn0 >> 11;                        // 0=A, 1=dt, 2=rawB
    const int colb = (bn0 & 2047) + wnBase + (lane & 15);
    const int rowb = bm0 + wmBase + ((lane >> 4) << 2);

    if (seg == 0) {
        float bias[4];
#pragma unroll
        for (int n = 0; n < 4; n++) bias[n] = bA[colb + n * 16];
#pragma unroll
        for (int m = 0; m < 8; m++)
#pragma unroll
            for (int n = 0; n < 4; n++)
#pragma unroll
                for (int r = 0; r < 4; r++) {
                    size_t idx = (size_t)(rowb + m * 16 + r) * D_DIM + colb + n * 16;
                    outA[idx] = 1.0f / (1.0f + __expf(-(acc[m][n][r] + bias[n])));
                }
    } else if (seg == 1) {
        float bias[4], sc[4];
#pragma unroll
        for (int n = 0; n < 4; n++) { bias[n] = bdt[colb + n * 16]; sc[n] = scales[colb + n * 16]; }
#pragma unroll
        for (int m = 0; m < 8; m++)
#pragma unroll
            for (int n = 0; n < 4; n++)
#pragma unroll
                for (int r = 0; r < 4; r++) {
                    size_t idx = (size_t)(rowb + m * 16 + r) * D_DIM + colb + n * 16;
                    float xx = acc[m][n][r] + bias[n];
                    float sp = xx > 0.f ? xx + log1pf(__expf(-xx)) : log1pf(__expf(xx));
                    outDT[idx] = sp * 0.1f * sc[n];
                }
    } else {
        float bias[4];
#pragma unroll
        for (int n = 0; n < 4; n++) bias[n] = bB[colb + n * 16];
#pragma unroll
        for (int m = 0; m < 8; m++)
#pragma unroll
            for (int n = 0; n < 4; n++)
#pragma unroll
                for (int r = 0; r < 4; r++) {
                    size_t idx = (size_t)(rowb + m * 16 + r) * D_DIM + colb + n * 16;
                    outB[idx] = acc[m][n][r] + bias[n];
                }
    }
}

// ---------------- scan pass 1: per-chunk affine aggregates ----------------
__global__ __launch_bounds__(256) void scan_pass1_kernel(
    const float* __restrict__ Aarr, const float* __restrict__ Braw,
    const float* __restrict__ dtarr, float4* __restrict__ agg)
{
    int tid = blockIdx.x * 256 + threadIdx.x;   // 131072
    int d = tid & (D_DIM - 1);
    int c = (tid >> 11) & (NCH - 1);
    int b = tid >> 15;
    size_t base = ((size_t)b * L_SEQ + c * CHUNK) * D_DIM + d;
    float P = 1.f, R = 0.f, U = 0.f, Wg = 0.f;
#pragma unroll 4
    for (int tt = 0; tt < CHUNK; tt++) {
        size_t idx = base + (size_t)tt * D_DIM;
        float a = Aarr[idx], rb = Braw[idx], dt = dtarr[idx];
        float bv = rb * dt;
        float da = dt * a;
        R = da * P + R;
        Wg = da * U + dt * bv + Wg;
        U = a * U + bv;
        P = a * P;
    }
    agg[tid] = make_float4(P, R, U, Wg);
}

// ---------------- scan pass 2: combine chunk aggregates ----------------
__global__ __launch_bounds__(256) void scan_pass2_kernel(
    const float4* __restrict__ agg, float2* __restrict__ pre)
{
    int tid = blockIdx.x * 256 + threadIdx.x;   // 8192
    int d = tid & (D_DIM - 1);
    int b = tid >> 11;
    float v = 0.f, x = 0.f;
#pragma unroll
    for (int c = 0; c < NCH; c++) {
        int i = ((b * NCH + c) << 11) + d;
        float4 g = agg[i];
        pre[i] = make_float2(v, x);
        float vn = g.x * v + g.z;
        x = g.y * v + x + g.w;
        v = vn;
    }
}

// ---------------- scan pass 3: replay chunk, write outputs in place ----------------
__global__ __launch_bounds__(256) void scan_pass3_kernel(
    const float* __restrict__ dtarr, const float2* __restrict__ pre,
    float* __restrict__ xout, float* __restrict__ vout)
{
    int tid = blockIdx.x * 256 + threadIdx.x;
    int d = tid & (D_DIM - 1);
    int c = (tid >> 11) & (NCH - 1);
    int b = tid >> 15;
    float2 s = pre[((b * NCH + c) << 11) + d];
    float v = s.x, x = s.y;
    size_t base = ((size_t)b * L_SEQ + c * CHUNK) * D_DIM + d;
#pragma unroll 4
    for (int tt = 0; tt < CHUNK; tt++) {
        size_t idx = base + (size_t)tt * D_DIM;
        float a = xout[idx];
        float rb = vout[idx];
        float dt = dtarr[idx];
        v = a * v + rb * dt;
        x = x + v * dt;
        vout[idx] = v;
        xout[idx] = x;
    }
}

extern "C" void kernel_launch(void* const* d_in, const int* in_sizes, int n_in,
                              void* d_out, int out_size, void* d_ws, size_t ws_size,
                              hipStream_t stream) {
    // inputs: 0:x 1:v 2:force 3:WA 4:bA 5:WB 6:bB 7:Wdt 8:bdt 9:scales
    const float* force  = (const float*)d_in[2];
    const float* WA     = (const float*)d_in[3];
    const float* bA     = (const float*)d_in[4];
    const float* WB     = (const float*)d_in[5];
    const float* bB     = (const float*)d_in[6];
    const float* Wdt    = (const float*)d_in[7];
    const float* bdt    = (const float*)d_in[8];
    const float* scales = (const float*)d_in[9];

    float* xout = (float*)d_out;                          // x_seq [8192*2048]
    float* vout = xout + (size_t)M_ROWS * D_DIM;          // v_seq

    char* ws = (char*)d_ws;
    bf16_t* fbf = (bf16_t*)ws;                                     // 32 MB
    bf16_t* wt  = (bf16_t*)(ws + (size_t)33554432);                // 24 MB
    float*  dtv = (float*)(ws + (size_t)33554432 + 25165824);      // 64 MB
    float4* agg = (float4*)(ws + (size_t)33554432 + 25165824 + 67108864); // 2 MB
    float2* pre = (float2*)(ws + (size_t)33554432 + 25165824 + 67108864 + 2097152); // 1 MB

    // 1) force -> bf16
    {
        int n4 = M_ROWS * D_DIM / 4;
        cvt_bf16_kernel<<<n4 / 256, 256, 0, stream>>>(force, fbf, n4);
    }
    // 2) transpose + convert weights into concat [6144][2048]: A | dt | B
    {
        dim3 grid(D_DIM / 32, D_DIM / 32), block(32, 8);
        transpose_w_kernel<<<grid, block, 0, stream>>>(WA,  wt);
        transpose_w_kernel<<<grid, block, 0, stream>>>(Wdt, wt + (size_t)D_DIM * D_DIM);
        transpose_w_kernel<<<grid, block, 0, stream>>>(WB,  wt + (size_t)2 * D_DIM * D_DIM);
    }
    // 3) fused GEMM + activations (256^2 8-phase)
    {
        dim3 grid((M_ROWS / 256) * (NT_COLS / 256));      // 32*24 = 768
        gemm_fused_kernel<<<grid, 512, 0, stream>>>(fbf, wt, bA, bdt, bB, scales,
                                                    xout, dtv, vout);
    }
    // 4-6) chunked associative scan
    scan_pass1_kernel<<<(B_SZ * NCH * D_DIM) / 256, 256, 0, stream>>>(xout, vout, dtv, agg);
    scan_pass2_kernel<<<(B_SZ * D_DIM) / 256, 256, 0, stream>>>(agg, pre);
    scan_pass3_kernel<<<(B_SZ * NCH * D_DIM) / 256, 256, 0, stream>>>(dtv, pre, xout, vout);
}